// Round 3
// baseline (70.354 us; speedup 1.0000x reference)
//
#include <hip/hip_runtime.h>

#define BINS  256
#define NCOPY 8           // bank-spread copies, indexed by lane&7 -> 16 KB LDS total
#define BLOCK 256
#define GRID  2048        // 8 blocks/CU on 256 CUs; 8*16KB=128KB <= 160KB LDS/CU

__device__ __forceinline__ void bin8(float4 a, float4 b,
                                     unsigned int* h1c, unsigned int* h2c)
{
    const float* av = &a.x;
    const float* bv = &b.x;
#pragma unroll
    for (int j = 0; j < 4; ++j) {
        float x = av[j];
        if (x >= 0.0f && x <= 1.0f) {
            int bin = (int)floorf(x * 256.0f);   // exact: matches JAX floor(x*256)
            bin = bin > 255 ? 255 : bin;
            atomicAdd(&h1c[bin * NCOPY], 1u);
        }
        float y = bv[j];
        if (y >= 0.0f && y <= 1.0f) {
            int bin = (int)floorf(y * 256.0f);
            bin = bin > 255 ? 255 : bin;
            atomicAdd(&h2c[bin * NCOPY], 1u);
        }
    }
}

// Pass 1: exact integer histograms of both images, one streaming pass.
// LDS layout lh[img][bin][copy], copy = lane&7:
//   bank = ((bin&3)<<3) | copy -> 8 lanes/copy spread over 4 bank groups (~2/bank, free);
//   same-address collision needs same copy AND same bin (~1/256 for random data).
__global__ __launch_bounds__(BLOCK, 8) void hist_kernel(
    const float* __restrict__ img1, const float* __restrict__ img2,
    unsigned int* __restrict__ g_h1, unsigned int* __restrict__ g_h2,
    long long n)
{
    __shared__ unsigned int lh[2][BINS][NCOPY];

    const int tid  = threadIdx.x;
    const int copy = tid & (NCOPY - 1);

    for (int i = tid; i < 2 * BINS * NCOPY; i += BLOCK)
        ((unsigned int*)lh)[i] = 0u;
    __syncthreads();

    const long long n4     = n >> 2;
    const long long stride = (long long)gridDim.x * BLOCK;
    const float4* p1 = (const float4*)img1;
    const float4* p2 = (const float4*)img2;

    unsigned int* h1c = &lh[0][0][copy];
    unsigned int* h2c = &lh[1][0][copy];

    long long i = (long long)blockIdx.x * BLOCK + tid;
    const long long trips = n4 / stride;   // uniform trip count: no bounds checks in loop

    if (trips > 0) {
        // software pipeline: next iteration's loads are in flight during atomics
        float4 a = p1[i];
        float4 b = p2[i];
        for (long long t = 1; t < trips; ++t) {
            const long long i2 = i + stride;
            float4 a2 = p1[i2];
            float4 b2 = p2[i2];
            bin8(a, b, h1c, h2c);
            a = a2; b = b2; i = i2;
        }
        bin8(a, b, h1c, h2c);
        i += stride;
    }
    // remainder float4s (threads with one extra element)
    if (i < n4) {
        float4 a = p1[i];
        float4 b = p2[i];
        bin8(a, b, h1c, h2c);
    }
    // scalar tail (n % 4), block 0 only
    if (blockIdx.x == 0) {
        for (long long k = (n4 << 2) + tid; k < n; k += BLOCK) {
            float x = img1[k];
            if (x >= 0.0f && x <= 1.0f) {
                int bin = (int)floorf(x * 256.0f);
                bin = bin > 255 ? 255 : bin;
                atomicAdd(&h1c[bin * NCOPY], 1u);
            }
            float y = img2[k];
            if (y >= 0.0f && y <= 1.0f) {
                int bin = (int)floorf(y * 256.0f);
                bin = bin > 255 ? 255 : bin;
                atomicAdd(&h2c[bin * NCOPY], 1u);
            }
        }
    }

    __syncthreads();

    // reduce copies, flush to global (device-scope atomics)
    for (int b = tid; b < BINS; b += BLOCK) {
        unsigned int s1 = 0u, s2 = 0u;
#pragma unroll
        for (int c = 0; c < NCOPY; ++c) { s1 += lh[0][b][c]; s2 += lh[1][b][c]; }
        if (s1) atomicAdd(&g_h1[b], s1);
        if (s2) atomicAdd(&g_h2[b], s2);
    }
}

// Pass 2: loss = sum_i |c1[i]/N1 - c2[i]/N2| / 256, double precision.
__global__ __launch_bounds__(BINS) void finalize_kernel(
    const unsigned int* __restrict__ h1, const unsigned int* __restrict__ h2,
    float* __restrict__ out)
{
    const int tid = threadIdx.x;          // one thread per bin
    const unsigned int c1 = h1[tid];
    const unsigned int c2 = h2[tid];

    __shared__ unsigned int s1[4], s2[4];
    __shared__ double sd[4];

    unsigned int r1 = c1, r2 = c2;
#pragma unroll
    for (int off = 32; off > 0; off >>= 1) {
        r1 += __shfl_down(r1, off);
        r2 += __shfl_down(r2, off);
    }
    if ((tid & 63) == 0) { s1[tid >> 6] = r1; s2[tid >> 6] = r2; }
    __syncthreads();

    const double N1 = (double)(s1[0] + s1[1] + s1[2] + s1[3]);
    const double N2 = (double)(s2[0] + s2[1] + s2[2] + s2[3]);

    double d = fabs((double)c1 / N1 - (double)c2 / N2);
#pragma unroll
    for (int off = 32; off > 0; off >>= 1)
        d += __shfl_down(d, off);
    if ((tid & 63) == 0) sd[tid >> 6] = d;
    __syncthreads();

    if (tid == 0) {
        double tot = sd[0] + sd[1] + sd[2] + sd[3];
        out[0] = (float)(tot / (double)BINS);
    }
}

extern "C" void kernel_launch(void* const* d_in, const int* in_sizes, int n_in,
                              void* d_out, int out_size, void* d_ws, size_t ws_size,
                              hipStream_t stream) {
    const float* img1 = (const float*)d_in[0];
    const float* img2 = (const float*)d_in[1];
    const long long n = (long long)in_sizes[0];

    unsigned int* g_h1 = (unsigned int*)d_ws;
    unsigned int* g_h2 = g_h1 + BINS;

    hipMemsetAsync(d_ws, 0, 2 * BINS * sizeof(unsigned int), stream);

    const long long n4 = n >> 2;
    int blocks = (int)((n4 + BLOCK - 1) / BLOCK);
    if (blocks > GRID) blocks = GRID;
    if (blocks < 1) blocks = 1;

    hist_kernel<<<blocks, BLOCK, 0, stream>>>(img1, img2, g_h1, g_h2, n);
    finalize_kernel<<<1, BINS, 0, stream>>>(g_h1, g_h2, (float*)d_out);
}